// Round 7
// baseline (2944.943 us; speedup 1.0000x reference)
//
#include <hip/hip_runtime.h>

// Point2Voxel: scatter-mean of point features into a B x 64^3 voxel grid.
// Outputs (flat, in order): masked_pc[N*3], voxel_feats[B*V*32],
// voxel_counts[B*V], inst_flag[B]  -- all float32.
//
// Binning matches XLA's compiled arithmetic: `t / 0.05` canonicalized to
// `t * 20.0f` (separate f32 roundings, NO FMA -> contract(off) LOAD-BEARING).
// Evidence: R2 (f32 div) 2.36, R3 (f64 div) 2.80, R4 (mul) PASS 0.0039.
//
// R7 scheme: build per-voxel linked lists (atomicExch push), then SPLIT the
// gather: p2v_classify streams zeros for empty voxels (no divergence, NT
// stores) and compacts non-empty voxels into a worklist; p2v_gather_work
// grid-strides the worklist doing the latency-bound list walk. R6 fused
// both -> streaming writes stalled behind pointer-chase exec masks.
// NOTE: measured dur_us includes ~180us of harness 0xAA re-poison fill.

static constexpr int kNX  = 64;
static constexpr int kNYZ = 64 * 64;
static constexpr int kV   = 64 * 64 * 64;
static constexpr int kB   = 8;
static constexpr int kC   = 32;

// ---------------- fast path ----------------

// Kernel A: per-point. masked_pc, validity, list push, inst_flag.
__global__ void __launch_bounds__(256) p2v_build(
    const float* __restrict__ pc, const int* __restrict__ bid,
    float* __restrict__ masked_pc, int* __restrict__ head,
    int* __restrict__ nxt, float* __restrict__ inst_flag, int n)
{
#pragma clang fp contract(off) reassociate(off)
  int i = blockIdx.x * blockDim.x + threadIdx.x;
  if (i >= n) return;

  const float HALF     = (float)(0.5 * 64 * 0.05);  // 1.60000002384f
  const float INV_UNIT = 20.0f;                      // XLA: /0.05 -> *20.0f

  float x = pc[3 * i + 0];
  float y = pc[3 * i + 1];
  float z = pc[3 * i + 2];

  bool valid = (fabsf(x) <= HALF) && (fabsf(y) <= HALF) && (fabsf(z) <= HALF);

  masked_pc[3 * i + 0] = valid ? x : 0.0f;
  masked_pc[3 * i + 1] = valid ? y : 0.0f;
  masked_pc[3 * i + 2] = valid ? z : 0.0f;

  if (!valid) return;

  float tx = x + HALF;
  float ty = y + HALF;
  float tz = z + HALF;
  int ix = (int)(tx * INV_UNIT);
  int iy = (int)(ty * INV_UNIT);
  int iz = (int)(tz * INV_UNIT);
  ix = min(max(ix, 0), kNX - 1);
  iy = min(max(iy, 0), kNX - 1);
  iz = min(max(iz, 0), kNX - 1);

  int b = bid[i];
  int lin = b * kV + ix * kNYZ + iy * kNX + iz;

  nxt[i] = atomicExch(head + lin, i);  // lock-free stack push
  inst_flag[b] = 1.0f;                 // benign race: same value
}

// Kernel B1: classify + stream. 8 lanes per voxel (lane owns 4 channels).
// Empty voxel: nontemporal zero write (pure stream, no divergence stall).
// Non-empty: lane 0 pushes v to the worklist (wave-aggregated atomicAdd).
__global__ void __launch_bounds__(256) p2v_classify(
    const int* __restrict__ head, float* __restrict__ voxel_feats,
    float* __restrict__ voxel_counts, int* __restrict__ worklist,
    int* __restrict__ counter)
{
  int gid = blockIdx.x * blockDim.x + threadIdx.x;  // < B*V*8
  int v  = gid >> 3;
  int c4 = (gid & 7) * 4;
  if (v >= kB * kV) return;

  int h = head[v];
  if (h < 0) {
    float* p = voxel_feats + (size_t)v * kC + c4;
    __builtin_nontemporal_store(0.0f, p + 0);
    __builtin_nontemporal_store(0.0f, p + 1);
    __builtin_nontemporal_store(0.0f, p + 2);
    __builtin_nontemporal_store(0.0f, p + 3);
    if (c4 == 0) voxel_counts[v] = 0.0f;
  } else if (c4 == 0) {
    int slot = atomicAdd(counter, 1);  // LLVM wave-aggregates this
    worklist[slot] = v;
  }
}

// Kernel B2: walk the compacted worklist. Grid-stride, 8 lanes per voxel.
__global__ void __launch_bounds__(256) p2v_gather_work(
    const float* __restrict__ feat, const int* __restrict__ head,
    const int* __restrict__ nxt, const int* __restrict__ worklist,
    const int* __restrict__ counter, float* __restrict__ voxel_feats,
    float* __restrict__ voxel_counts)
{
#pragma clang fp contract(off) reassociate(off)
  long long total = (long long)(*counter) * 8;
  long long stride = (long long)gridDim.x * blockDim.x;
  for (long long g = blockIdx.x * (long long)blockDim.x + threadIdx.x;
       g < total; g += stride) {
    int w  = (int)(g >> 3);
    int c4 = ((int)g & 7) * 4;
    int v  = worklist[w];

    float4 sum = make_float4(0.f, 0.f, 0.f, 0.f);
    int cnt = 0;
    for (int h = head[v]; h >= 0; h = nxt[h]) {
      const float4 f = *(const float4*)(feat + (size_t)h * kC + c4);
      sum.x += f.x; sum.y += f.y; sum.z += f.z; sum.w += f.w;
      ++cnt;
    }

    if (cnt >= 2) {
      double dc = (double)cnt;  // IEEE f32-equivalent quotient via double
      sum.x = (float)((double)sum.x / dc);
      sum.y = (float)((double)sum.y / dc);
      sum.z = (float)((double)sum.z / dc);
      sum.w = (float)((double)sum.w / dc);
    }
    float* p = voxel_feats + (size_t)v * kC + c4;
    __builtin_nontemporal_store(sum.x, p + 0);
    __builtin_nontemporal_store(sum.y, p + 1);
    __builtin_nontemporal_store(sum.z, p + 2);
    __builtin_nontemporal_store(sum.w, p + 3);
    if (c4 == 0) voxel_counts[v] = (float)cnt;
  }
}

// ---------------- fallback path (ws too small): R5 atomic scheme ----------

__global__ void __launch_bounds__(256) p2v_main_fb(
    const float* __restrict__ pc, const float* __restrict__ feat,
    const int* __restrict__ bid, float* __restrict__ masked_pc,
    float* __restrict__ voxel_feats, float* __restrict__ voxel_counts,
    float* __restrict__ inst_flag, int n)
{
#pragma clang fp contract(off) reassociate(off)
  int i = blockIdx.x * blockDim.x + threadIdx.x;
  if (i >= n) return;
  const float HALF = (float)(0.5 * 64 * 0.05);
  const float INV_UNIT = 20.0f;
  float x = pc[3 * i + 0], y = pc[3 * i + 1], z = pc[3 * i + 2];
  bool valid = (fabsf(x) <= HALF) && (fabsf(y) <= HALF) && (fabsf(z) <= HALF);
  masked_pc[3 * i + 0] = valid ? x : 0.0f;
  masked_pc[3 * i + 1] = valid ? y : 0.0f;
  masked_pc[3 * i + 2] = valid ? z : 0.0f;
  if (!valid) return;
  int ix = (int)((x + HALF) * INV_UNIT);
  int iy = (int)((y + HALF) * INV_UNIT);
  int iz = (int)((z + HALF) * INV_UNIT);
  ix = min(max(ix, 0), kNX - 1);
  iy = min(max(iy, 0), kNX - 1);
  iz = min(max(iz, 0), kNX - 1);
  int b = bid[i];
  size_t lin = (size_t)b * kV + (size_t)(ix * kNYZ + iy * kNX + iz);
  atomicAdd(voxel_counts + lin, 1.0f);
  inst_flag[b] = 1.0f;
  float* dst = voxel_feats + lin * kC;
  const float* src = feat + (size_t)i * kC;
#pragma unroll
  for (int c = 0; c < kC; ++c) atomicAdd(dst + c, src[c]);
}

__global__ void __launch_bounds__(256) p2v_finalize_fb(
    float* __restrict__ voxel_feats, const float* __restrict__ voxel_counts)
{
#pragma clang fp contract(off) reassociate(off)
  int v = blockIdx.x * blockDim.x + threadIdx.x;
  if (v >= kB * kV) return;
  float c = voxel_counts[v];
  if (c >= 2.0f) {
    float* p = voxel_feats + (size_t)v * kC;
#pragma unroll
    for (int k = 0; k < kC; ++k) p[k] = (float)((double)p[k] / (double)c);
  }
}

// ---------------------------------------------------------------------------

extern "C" void kernel_launch(void* const* d_in, const int* in_sizes, int n_in,
                              void* d_out, int out_size, void* d_ws, size_t ws_size,
                              hipStream_t stream) {
  const float* pc   = (const float*)d_in[0];
  const float* feat = (const float*)d_in[1];
  const int*   bid  = (const int*)d_in[2];
  float* out = (float*)d_out;

  int n = in_sizes[0] / 3;

  float* masked_pc    = out;
  float* voxel_feats  = out + (size_t)3 * n;
  float* voxel_counts = voxel_feats + (size_t)kB * kV * kC;
  float* inst_flag    = voxel_counts + (size_t)kB * kV;

  const int block = 256;
  int nv = kB * kV;

  // ws layout: head[nv] | nxt[n] | worklist[nv] | counter[1]
  size_t need = ((size_t)nv * 2 + (size_t)n + 1) * sizeof(int);

  if (ws_size >= need) {
    int* head     = (int*)d_ws;
    int* nxt      = head + nv;
    int* worklist = nxt + n;
    int* counter  = worklist + nv;

    hipMemsetAsync(head, 0xFF, (size_t)nv * sizeof(int), stream);
    hipMemsetAsync(counter, 0, sizeof(int), stream);
    hipMemsetAsync(inst_flag, 0, kB * sizeof(float), stream);

    p2v_build<<<(n + block - 1) / block, block, 0, stream>>>(
        pc, bid, masked_pc, head, nxt, inst_flag, n);

    long long ng = (long long)nv * 8;  // 8 lanes per voxel
    p2v_classify<<<(int)((ng + block - 1) / block), block, 0, stream>>>(
        head, voxel_feats, voxel_counts, worklist, counter);

    p2v_gather_work<<<2048, block, 0, stream>>>(
        feat, head, nxt, worklist, counter, voxel_feats, voxel_counts);
  } else {
    // Fallback: proven R5 atomic scheme (needs no ws).
    size_t tail_floats = (size_t)nv * kC + (size_t)nv + kB;
    hipMemsetAsync(voxel_feats, 0, tail_floats * sizeof(float), stream);
    p2v_main_fb<<<(n + block - 1) / block, block, 0, stream>>>(
        pc, feat, bid, masked_pc, voxel_feats, voxel_counts, inst_flag, n);
    p2v_finalize_fb<<<(nv + block - 1) / block, block, 0, stream>>>(
        voxel_feats, voxel_counts);
  }
}